// Round 9
// baseline (124.254 us; speedup 1.0000x reference)
//
#include <hip/hip_runtime.h>
#include <hip/hip_bf16.h>

#define B_ 4
#define T_ 256
#define S_ 256
#define D_ 512
#define TB 2   // t's per attention block

typedef __bf16 bf16x8 __attribute__((ext_vector_type(8)));
typedef float  floatx4 __attribute__((ext_vector_type(4)));

#define C2F 2.885390081777926f  // 2*log2(e)

static __device__ __forceinline__ unsigned short f2bf(float x) {
    __hip_bfloat16 h = __float2bfloat16(x);
    return *reinterpret_cast<unsigned short*>(&h);
}
static __device__ __forceinline__ float asf(unsigned int u) {
    float f; __builtin_memcpy(&f, &u, 4); return f;
}

// ---------------------------------------------------------------------------
// gemm3: fused convert + MFMA GEMM, replaces prep + gemm2 (one dispatch).
// Four z-slices, each C[1024 x 512] = A[1024 x 512] @ W-block[512 x 512]:
//   z0: wqs = C2*(output@Wq + bq)     fp32          [mode 1]
//   z1: uhb = bf16 C2*(context@Wc)    [b][d/8][s][8] [mode 3]
//   z2: OB  = output@Wout[512:] + bout fp32          [mode 4]
//   z3: CWb = bf16 context@Wout[:512] natural       [mode 5]
// Block = 64m x 64n, 256 thr (4 waves, each 32m x 32n = 2x2 16x16 frags).
// K-loop: 16 chunks of 32; fp32 inputs converted inline to bf16 and staged
// in LDS in MFMA FRAGMENT ORDER -> frag load = one contiguous ds_read_b128.
//   A stage: thread (sm=tid>>2, skq=tid&3) reads A[m0+sm][k0+8skq..+8) (32B
//            contiguous) -> Af[sm>>4][(sm&15)|(skq<<4)][0..7].
//   B stage: thread (sn=tid&63, sk8=(tid>>6)*8) reads 8 k-strided W elems
//            W[k0+sk8+j][n0+sn] (lane-coalesced 256B across sn) ->
//            Bf[sn>>4][(sn&15)|((sk8>>3)<<4)][0..7].
// ---------------------------------------------------------------------------
struct G3 {
    const float* A;      // (1024, 512) fp32 activations
    const float* W;      // (k, n) row-major fp32, n-stride 512
    int krow0;           // k-row offset into W
    const float* aux;    // bias or null
    void* C;
    int mode;
};

__global__ __launch_bounds__(256) void gemm3(G3 g0, G3 g1, G3 g2, G3 g3)
{
    const int z = blockIdx.z;
    G3 g = (z == 0) ? g0 : (z == 1) ? g1 : (z == 2) ? g2 : g3;

    const int tid  = threadIdx.x;
    const int wave = tid >> 6, lane = tid & 63;
    const int l15  = lane & 15, quad = lane >> 4;
    const int wm   = wave >> 1, wn = wave & 1;
    const int m0   = blockIdx.y * 64;
    const int n0   = blockIdx.x * 64;

    __shared__ unsigned short Af[4 * 64 * 8];  // 4 KB, frag order
    __shared__ unsigned short Bf[4 * 64 * 8];  // 4 KB, frag order

    const int sm  = tid >> 2, skq = tid & 3;       // A staging coords
    const int sn  = tid & 63, sk8 = (tid >> 6) * 8; // B staging coords

    const float* Abase = g.A + (size_t)(m0 + sm) * 512 + skq * 8;
    const float* Wbase = g.W + (size_t)(g.krow0 + sk8) * 512 + n0 + sn;

    unsigned short* Awr = Af + ((size_t)(sm >> 4) * 64 + ((sm & 15) | (skq << 4))) * 8;
    unsigned short* Bwr = Bf + ((size_t)(sn >> 4) * 64 + ((sn & 15) | ((sk8 >> 3) << 4))) * 8;

    const unsigned short* Ard0 = Af + ((size_t)(wm * 2 + 0) * 64 + lane) * 8;
    const unsigned short* Ard1 = Af + ((size_t)(wm * 2 + 1) * 64 + lane) * 8;
    const unsigned short* Brd0 = Bf + ((size_t)(wn * 2 + 0) * 64 + lane) * 8;
    const unsigned short* Brd1 = Bf + ((size_t)(wn * 2 + 1) * 64 + lane) * 8;

    floatx4 acc[2][2];
    #pragma unroll
    for (int i = 0; i < 2; ++i)
        #pragma unroll
        for (int j = 0; j < 2; ++j) acc[i][j] = (floatx4){0.f, 0.f, 0.f, 0.f};

    for (int chunk = 0; chunk < 16; ++chunk) {
        const int k0 = chunk * 32;
        // issue global loads (latency overlaps the barrier wait)
        float4 a0 = *(const float4*)(Abase + k0);
        float4 a1 = *(const float4*)(Abase + k0 + 4);
        float bcol[8];
        #pragma unroll
        for (int j = 0; j < 8; ++j)
            bcol[j] = Wbase[(size_t)(k0 + j) * 512];

        __syncthreads();  // prev chunk's frag reads done
        uint4 pa;
        pa.x = (unsigned)f2bf(a0.x) | ((unsigned)f2bf(a0.y) << 16);
        pa.y = (unsigned)f2bf(a0.z) | ((unsigned)f2bf(a0.w) << 16);
        pa.z = (unsigned)f2bf(a1.x) | ((unsigned)f2bf(a1.y) << 16);
        pa.w = (unsigned)f2bf(a1.z) | ((unsigned)f2bf(a1.w) << 16);
        *(uint4*)Awr = pa;
        uint4 pb;
        pb.x = (unsigned)f2bf(bcol[0]) | ((unsigned)f2bf(bcol[1]) << 16);
        pb.y = (unsigned)f2bf(bcol[2]) | ((unsigned)f2bf(bcol[3]) << 16);
        pb.z = (unsigned)f2bf(bcol[4]) | ((unsigned)f2bf(bcol[5]) << 16);
        pb.w = (unsigned)f2bf(bcol[6]) | ((unsigned)f2bf(bcol[7]) << 16);
        *(uint4*)Bwr = pb;
        __syncthreads();

        bf16x8 fa0 = *(const bf16x8*)Ard0;
        bf16x8 fa1 = *(const bf16x8*)Ard1;
        bf16x8 fb0 = *(const bf16x8*)Brd0;
        bf16x8 fb1 = *(const bf16x8*)Brd1;
        acc[0][0] = __builtin_amdgcn_mfma_f32_16x16x32_bf16(fa0, fb0, acc[0][0], 0, 0, 0);
        acc[0][1] = __builtin_amdgcn_mfma_f32_16x16x32_bf16(fa0, fb1, acc[0][1], 0, 0, 0);
        acc[1][0] = __builtin_amdgcn_mfma_f32_16x16x32_bf16(fa1, fb0, acc[1][0], 0, 0, 0);
        acc[1][1] = __builtin_amdgcn_mfma_f32_16x16x32_bf16(fa1, fb1, acc[1][1], 0, 0, 0);
    }

    #pragma unroll
    for (int mi = 0; mi < 2; ++mi) {
        #pragma unroll
        for (int ni = 0; ni < 2; ++ni) {
            const int col = n0 + wn * 32 + ni * 16 + l15;
            const int rbase = m0 + wm * 32 + mi * 16 + quad * 4;
            if (g.mode == 3) {
                unsigned short* Cb = (unsigned short*)g.C;
                #pragma unroll
                for (int r = 0; r < 4; ++r) {
                    int row = rbase + r, bb = row >> 8, ss = row & 255;
                    Cb[((size_t)(bb * 64 + (col >> 3)) * 256 + ss) * 8 + (col & 7)]
                        = f2bf(C2F * acc[mi][ni][r]);
                }
            } else if (g.mode == 5) {
                unsigned short* Cb = (unsigned short*)g.C;
                #pragma unroll
                for (int r = 0; r < 4; ++r)
                    Cb[(size_t)(rbase + r) * 512 + col] = f2bf(acc[mi][ni][r]);
            } else {
                float* Cf = (float*)g.C;
                float bv = g.aux ? g.aux[col] : 0.0f;
                #pragma unroll
                for (int r = 0; r < 4; ++r) {
                    float val = acc[mi][ni][r] + bv;
                    if (g.mode == 1) val *= C2F;
                    Cf[(size_t)(rbase + r) * 512 + col] = val;
                }
            }
        }
    }
}

// ---------------------------------------------------------------------------
// Fused score + masked softmax + out-projection (unchanged from R8).
// 1024 threads; 512 blocks. Thread (s=tid&255, h=tid>>8) owns d-quarter.
// p = exp2(-C2F*A) (shift-invariant softmax; no max reduction).
// ---------------------------------------------------------------------------
__global__ __launch_bounds__(1024) void attn_fused(
    const float* __restrict__ wqs,            // (B,T,D) pre-scaled fp32
    const unsigned short* __restrict__ uhb,   // (B,D/8,S,8) pre-scaled bf16
    const unsigned short* __restrict__ CWb,   // (B,S,D) bf16
    const float* __restrict__ OB,             // (B,T,D) fp32
    const int*   __restrict__ mask,           // (B,S)
    const float* __restrict__ v,              // (D)
    float* __restrict__ attn_out,             // (B,T,S) fp32
    float* __restrict__ out)                  // (B,T,D) fp32
{
    const int bg  = blockIdx.x;
    const int b   = bg / (T_ / TB);
    const int t0  = (bg % (T_ / TB)) * TB;
    const int tid = threadIdx.x;
    const int s   = tid & 255;
    const int h   = tid >> 8;    // 0..3

    __shared__ float  w_s[TB][D_];       // 4 KB
    __shared__ float  v_s[D_];           // 2 KB
    __shared__ float2 part[4][256];      // 8 KB
    __shared__ float2 wred[4];
    __shared__ float  a_s[TB][256];      // 2 KB
    __shared__ float  mixp[4][TB][D_];   // 16 KB

    if (tid < 512) {
        w_s[0][tid] = wqs[(size_t)(b * T_ + t0 + 0) * D_ + tid];
        w_s[1][tid] = wqs[(size_t)(b * T_ + t0 + 1) * D_ + tid];
        v_s[tid]    = v[tid];
    }
    __syncthreads();

    float acc0 = 0.f, acc1 = 0.f;
    const int dd0 = h * 16;
    const uint4* u4 = (const uint4*)(uhb + ((size_t)(b * 64 + dd0) * 256 + s) * 8);

    #pragma unroll 4
    for (int dd = 0; dd < 16; ++dd) {
        uint4 uu = u4[(size_t)dd * 256];
        float uf[8];
        uf[0] = asf(uu.x << 16); uf[1] = asf(uu.x & 0xffff0000u);
        uf[2] = asf(uu.y << 16); uf[3] = asf(uu.y & 0xffff0000u);
        uf[4] = asf(uu.z << 16); uf[5] = asf(uu.z & 0xffff0000u);
        uf[6] = asf(uu.w << 16); uf[7] = asf(uu.w & 0xffff0000u);

        const int dbase = (dd0 + dd) * 8;
        #pragma unroll
        for (int j = 0; j < 8; ++j) {
            float vv = v_s[dbase + j];
            float x0 = w_s[0][dbase + j] + uf[j];
            float x1 = w_s[1][dbase + j] + uf[j];
            float r0 = __builtin_amdgcn_rcpf(__builtin_amdgcn_exp2f(x0) + 1.0f);
            float r1 = __builtin_amdgcn_rcpf(__builtin_amdgcn_exp2f(x1) + 1.0f);
            acc0 = fmaf(vv, r0, acc0);
            acc1 = fmaf(vv, r1, acc1);
        }
    }
    part[h][s] = make_float2(acc0, acc1);
    __syncthreads();

    float p0 = 0.f, p1 = 0.f;
    if (tid < 256) {
        float A0 = part[0][tid].x + part[1][tid].x + part[2][tid].x + part[3][tid].x;
        float A1 = part[0][tid].y + part[1][tid].y + part[2][tid].y + part[3][tid].y;
        float keep = 1.0f - (float)mask[b * S_ + tid];
        p0 = __builtin_amdgcn_exp2f(-C2F * A0) * keep;
        p1 = __builtin_amdgcn_exp2f(-C2F * A1) * keep;
        float s0 = p0, s1 = p1;
        #pragma unroll
        for (int off = 1; off < 64; off <<= 1) {
            s0 += __shfl_xor(s0, off);
            s1 += __shfl_xor(s1, off);
        }
        if ((tid & 63) == 0) wred[tid >> 6] = make_float2(s0, s1);
    }
    __syncthreads();

    if (tid < 256) {
        float den0 = wred[0].x + wred[1].x + wred[2].x + wred[3].x;
        float den1 = wred[0].y + wred[1].y + wred[2].y + wred[3].y;
        float a0 = p0 * __builtin_amdgcn_rcpf(den0);
        float a1 = p1 * __builtin_amdgcn_rcpf(den1);
        attn_out[(size_t)(b * T_ + t0 + 0) * S_ + tid] = a0;
        attn_out[(size_t)(b * T_ + t0 + 1) * S_ + tid] = a1;
        a_s[0][tid] = a0;
        a_s[1][tid] = a1;
    }
    __syncthreads();

    const int d2 = tid & 255;
    const int sh = h * 64;
    const unsigned short* cw = CWb + ((size_t)(b * S_) + sh) * D_ + 2 * d2;
    float m[TB][2] = {};
    #pragma unroll 8
    for (int s2 = 0; s2 < 64; ++s2) {
        unsigned int cc = *(const unsigned int*)(cw + (size_t)s2 * D_);
        float c0 = asf(cc << 16), c1 = asf(cc & 0xffff0000u);
        #pragma unroll
        for (int t = 0; t < TB; ++t) {
            float a = a_s[t][sh + s2];
            m[t][0] = fmaf(a, c0, m[t][0]);
            m[t][1] = fmaf(a, c1, m[t][1]);
        }
    }
    #pragma unroll
    for (int t = 0; t < TB; ++t) {
        mixp[h][t][2 * d2]     = m[t][0];
        mixp[h][t][2 * d2 + 1] = m[t][1];
    }
    __syncthreads();

    {
        const int t = tid >> 9, d = tid & 511;
        size_t idx = (size_t)(b * T_ + t0 + t) * D_ + d;
        out[idx] = mixp[0][t][d] + mixp[1][t][d] + mixp[2][t][d] + mixp[3][t][d]
                 + OB[idx];
    }
}

extern "C" void kernel_launch(void* const* d_in, const int* in_sizes, int n_in,
                              void* d_out, int out_size, void* d_ws, size_t ws_size,
                              hipStream_t stream) {
    const float* output  = (const float*)d_in[0];
    const float* context = (const float*)d_in[1];
    const int*   mask    = (const int*)d_in[2];
    const float* Wq      = (const float*)d_in[3];
    const float* bq      = (const float*)d_in[4];
    const float* Wc      = (const float*)d_in[5];
    const float* v       = (const float*)d_in[6];
    const float* Wout    = (const float*)d_in[7];
    const float* bout    = (const float*)d_in[8];

    float* out  = (float*)d_out;                       // (B,T,D)
    float* attn = out + (size_t)B_ * T_ * D_;          // (B,T,S)

    char* ws = (char*)d_ws;
    float* wqs          = (float*)ws;                             // 2 MB
    float* OB           = (float*)(ws + (2u << 20));              // 2 MB
    unsigned short* uhb = (unsigned short*)(ws + (4u << 20));     // 1 MB
    unsigned short* CWb = (unsigned short*)(ws + (5u << 20));     // 1 MB

    // one dispatch: all four GEMMs with inline fp32->bf16 convert
    G3 gwq = { output,  Wq,     0, bq,      wqs, 1 };
    G3 guh = { context, Wc,     0, nullptr, uhb, 3 };
    G3 gob = { output,  Wout, 512, bout,    OB,  4 };
    G3 gcw = { context, Wout,   0, nullptr, CWb, 5 };
    gemm3<<<dim3(8, 16, 4), dim3(256), 0, stream>>>(gwq, guh, gob, gcw);

    // fused score + softmax + out-projection
    attn_fused<<<dim3(B_ * T_ / TB), dim3(1024), 0, stream>>>(
        wqs, uhb, CWb, OB, mask, v, attn, out);
}

// Round 11
// 123.741 us; speedup vs baseline: 1.0041x; 1.0041x over previous
//
#include <hip/hip_runtime.h>
#include <hip/hip_bf16.h>

#define B_ 4
#define T_ 256
#define S_ 256
#define D_ 512
#define TB 2   // t's per attention block

typedef __bf16 bf16x8 __attribute__((ext_vector_type(8)));
typedef float  floatx4 __attribute__((ext_vector_type(4)));

#define C2F 2.885390081777926f  // 2*log2(e)

static __device__ __forceinline__ unsigned short f2bf(float x) {
    __hip_bfloat16 h = __float2bfloat16(x);
    return *reinterpret_cast<unsigned short*>(&h);
}
static __device__ __forceinline__ float asf(unsigned int u) {
    float f; __builtin_memcpy(&f, &u, 4); return f;
}

// ---------------------------------------------------------------------------
// gemm4: fused convert + MFMA GEMM. 512 blocks x 1024 threads (16 waves),
// 2 blocks/CU = 32 waves/CU (vs R9 gemm3's 8). One 64m x 64n x K=512 tile
// per block; bid = z + 4*(nblk + 8*mblk). Four z-slices:
//   z0: wqs = C2*(output@Wq + bq)            fp32
//   z1: uhb = bf16 C2*(context@Wc)           [b][d/8][s][8]
//   z2: OB  = output@Wout[512:] + bout       fp32
//   z3: CWb = bf16 context@Wout[:512]        natural [row][col]
// K-loop: 16 chunks of 32; fp32 loaded (A: float2/thread, W: two n-coalesced
// rows/thread), converted inline to bf16, staged in LDS in MFMA fragment
// order; each wave owns one 16x16 frag -> 2 ds_read_b128 + 1 MFMA per chunk.
// ---------------------------------------------------------------------------
struct G4 {
    const float* A;      // (1024, 512) fp32 activations
    const float* W;      // (k, n) fp32, n-stride 512
    int krow0;
    const float* aux;    // bias or null
    void* C;
    int mode;
};

__global__ __launch_bounds__(1024, 8) void gemm4(G4 g0, G4 g1, G4 g2, G4 g3)
{
    const int tid = threadIdx.x;
    const int bid = blockIdx.x;

    const int z  = bid & 3;
    const int n0 = ((bid >> 2) & 7) * 64;
    const int m0 = (bid >> 5) * 64;

    G4 g = (z == 0) ? g0 : (z == 1) ? g1 : (z == 2) ? g2 : g3;

    __shared__ unsigned short Af[4 * 64 * 8];  // 4 KB, frag order
    __shared__ unsigned short Bf[4 * 64 * 8];  // 4 KB, frag order

    // staging: A chunk 64m x 32k, B chunk 32k x 64n; 2 elems/thread each
    const int am = tid >> 4;              // 0..63
    const int ak = (tid & 15) * 2;        // 0..30 even
    const int bn = tid & 63;
    const int bk = (tid >> 6) * 2;        // 0..30 even

    const float* Aptr = g.A + (size_t)(m0 + am) * 512 + ak;
    const float* Wptr = g.W + (size_t)(g.krow0 + bk) * 512 + n0 + bn;

    unsigned int* Awr = (unsigned int*)&Af[((am >> 4) * 64
                          + ((am & 15) | ((ak >> 3) << 4))) * 8 + (ak & 7)];
    unsigned int* Bwr = (unsigned int*)&Bf[((bn >> 4) * 64
                          + ((bn & 15) | ((bk >> 3) << 4))) * 8 + (bk & 7)];

    const int wave = tid >> 6, lane = tid & 63;
    const int l15 = lane & 15, quad = lane >> 4;
    const int mf = wave >> 2, nf = wave & 3;
    const unsigned short* Ard = &Af[(mf * 64 + lane) * 8];
    const unsigned short* Brd = &Bf[(nf * 64 + lane) * 8];

    floatx4 acc = (floatx4){0.f, 0.f, 0.f, 0.f};

    for (int chunk = 0; chunk < 16; ++chunk) {
        const int k0 = chunk * 32;
        float2 av = *(const float2*)(Aptr + k0);
        float  b0 = Wptr[(size_t)k0 * 512];
        float  b1 = Wptr[(size_t)k0 * 512 + 512];

        __syncthreads();   // prev chunk's frag reads done
        *Awr = (unsigned)f2bf(av.x) | ((unsigned)f2bf(av.y) << 16);
        *Bwr = (unsigned)f2bf(b0)   | ((unsigned)f2bf(b1)   << 16);
        __syncthreads();

        bf16x8 fa = *(const bf16x8*)Ard;
        bf16x8 fb = *(const bf16x8*)Brd;
        acc = __builtin_amdgcn_mfma_f32_16x16x32_bf16(fa, fb, acc, 0, 0, 0);
    }

    const int col = n0 + nf * 16 + l15;
    const int rbase = m0 + mf * 16 + quad * 4;
    if (g.mode == 3) {
        unsigned short* Cb = (unsigned short*)g.C;
        #pragma unroll
        for (int r = 0; r < 4; ++r) {
            int row = rbase + r, bb = row >> 8, ss = row & 255;
            Cb[((size_t)(bb * 64 + (col >> 3)) * 256 + ss) * 8 + (col & 7)]
                = f2bf(C2F * acc[r]);
        }
    } else if (g.mode == 5) {
        unsigned short* Cb = (unsigned short*)g.C;
        #pragma unroll
        for (int r = 0; r < 4; ++r)
            Cb[(size_t)(rbase + r) * 512 + col] = f2bf(acc[r]);
    } else {
        float* Cf = (float*)g.C;
        float bv = g.aux ? g.aux[col] : 0.0f;
        #pragma unroll
        for (int r = 0; r < 4; ++r) {
            float val = acc[r] + bv;
            if (g.mode == 1) val *= C2F;
            Cf[(size_t)(rbase + r) * 512 + col] = val;
        }
    }
}

// ---------------------------------------------------------------------------
// Fused score + masked softmax + out-projection (R8 verbatim, known-good).
// 1024 threads; 512 blocks. Thread (s=tid&255, h=tid>>8) owns d-quarter.
// p = exp2(-C2F*A) (shift-invariant softmax; no max reduction).
// ---------------------------------------------------------------------------
__global__ __launch_bounds__(1024) void attn_fused(
    const float* __restrict__ wqs,            // (B,T,D) pre-scaled fp32
    const unsigned short* __restrict__ uhb,   // (B,D/8,S,8) pre-scaled bf16
    const unsigned short* __restrict__ CWb,   // (B,S,D) bf16
    const float* __restrict__ OB,             // (B,T,D) fp32
    const int*   __restrict__ mask,           // (B,S)
    const float* __restrict__ v,              // (D)
    float* __restrict__ attn_out,             // (B,T,S) fp32
    float* __restrict__ out)                  // (B,T,D) fp32
{
    const int bg  = blockIdx.x;
    const int b   = bg / (T_ / TB);
    const int t0  = (bg % (T_ / TB)) * TB;
    const int tid = threadIdx.x;
    const int s   = tid & 255;
    const int h   = tid >> 8;    // 0..3

    __shared__ float  w_s[TB][D_];       // 4 KB
    __shared__ float  v_s[D_];           // 2 KB
    __shared__ float2 part[4][256];      // 8 KB
    __shared__ float2 wred[4];
    __shared__ float  a_s[TB][256];      // 2 KB
    __shared__ float  mixp[4][TB][D_];   // 16 KB

    if (tid < 512) {
        w_s[0][tid] = wqs[(size_t)(b * T_ + t0 + 0) * D_ + tid];
        w_s[1][tid] = wqs[(size_t)(b * T_ + t0 + 1) * D_ + tid];
        v_s[tid]    = v[tid];
    }
    __syncthreads();

    float acc0 = 0.f, acc1 = 0.f;
    const int dd0 = h * 16;
    const uint4* u4 = (const uint4*)(uhb + ((size_t)(b * 64 + dd0) * 256 + s) * 8);

    #pragma unroll 4
    for (int dd = 0; dd < 16; ++dd) {
        uint4 uu = u4[(size_t)dd * 256];
        float uf[8];
        uf[0] = asf(uu.x << 16); uf[1] = asf(uu.x & 0xffff0000u);
        uf[2] = asf(uu.y << 16); uf[3] = asf(uu.y & 0xffff0000u);
        uf[4] = asf(uu.z << 16); uf[5] = asf(uu.z & 0xffff0000u);
        uf[6] = asf(uu.w << 16); uf[7] = asf(uu.w & 0xffff0000u);

        const int dbase = (dd0 + dd) * 8;
        #pragma unroll
        for (int j = 0; j < 8; ++j) {
            float vv = v_s[dbase + j];
            float x0 = w_s[0][dbase + j] + uf[j];
            float x1 = w_s[1][dbase + j] + uf[j];
            float r0 = __builtin_amdgcn_rcpf(__builtin_amdgcn_exp2f(x0) + 1.0f);
            float r1 = __builtin_amdgcn_rcpf(__builtin_amdgcn_exp2f(x1) + 1.0f);
            acc0 = fmaf(vv, r0, acc0);
            acc1 = fmaf(vv, r1, acc1);
        }
    }
    part[h][s] = make_float2(acc0, acc1);
    __syncthreads();

    float p0 = 0.f, p1 = 0.f;
    if (tid < 256) {
        float A0 = part[0][tid].x + part[1][tid].x + part[2][tid].x + part[3][tid].x;
        float A1 = part[0][tid].y + part[1][tid].y + part[2][tid].y + part[3][tid].y;
        float keep = 1.0f - (float)mask[b * S_ + tid];
        p0 = __builtin_amdgcn_exp2f(-C2F * A0) * keep;
        p1 = __builtin_amdgcn_exp2f(-C2F * A1) * keep;
        float s0 = p0, s1 = p1;
        #pragma unroll
        for (int off = 1; off < 64; off <<= 1) {
            s0 += __shfl_xor(s0, off);
            s1 += __shfl_xor(s1, off);
        }
        if ((tid & 63) == 0) wred[tid >> 6] = make_float2(s0, s1);
    }
    __syncthreads();

    if (tid < 256) {
        float den0 = wred[0].x + wred[1].x + wred[2].x + wred[3].x;
        float den1 = wred[0].y + wred[1].y + wred[2].y + wred[3].y;
        float a0 = p0 * __builtin_amdgcn_rcpf(den0);
        float a1 = p1 * __builtin_amdgcn_rcpf(den1);
        attn_out[(size_t)(b * T_ + t0 + 0) * S_ + tid] = a0;
        attn_out[(size_t)(b * T_ + t0 + 1) * S_ + tid] = a1;
        a_s[0][tid] = a0;
        a_s[1][tid] = a1;
    }
    __syncthreads();

    const int d2 = tid & 255;
    const int sh = h * 64;
    const unsigned short* cw = CWb + ((size_t)(b * S_) + sh) * D_ + 2 * d2;
    float m[TB][2] = {};
    #pragma unroll 8
    for (int s2 = 0; s2 < 64; ++s2) {
        unsigned int cc = *(const unsigned int*)(cw + (size_t)s2 * D_);
        float c0 = asf(cc << 16), c1 = asf(cc & 0xffff0000u);
        #pragma unroll
        for (int t = 0; t < TB; ++t) {
            float a = a_s[t][sh + s2];
            m[t][0] = fmaf(a, c0, m[t][0]);
            m[t][1] = fmaf(a, c1, m[t][1]);
        }
    }
    #pragma unroll
    for (int t = 0; t < TB; ++t) {
        mixp[h][t][2 * d2]     = m[t][0];
        mixp[h][t][2 * d2 + 1] = m[t][1];
    }
    __syncthreads();

    {
        const int t = tid >> 9, d = tid & 511;
        size_t idx = (size_t)(b * T_ + t0 + t) * D_ + d;
        out[idx] = mixp[0][t][d] + mixp[1][t][d] + mixp[2][t][d] + mixp[3][t][d]
                 + OB[idx];
    }
}

extern "C" void kernel_launch(void* const* d_in, const int* in_sizes, int n_in,
                              void* d_out, int out_size, void* d_ws, size_t ws_size,
                              hipStream_t stream) {
    const float* output  = (const float*)d_in[0];
    const float* context = (const float*)d_in[1];
    const int*   mask    = (const int*)d_in[2];
    const float* Wq      = (const float*)d_in[3];
    const float* bq      = (const float*)d_in[4];
    const float* Wc      = (const float*)d_in[5];
    const float* v       = (const float*)d_in[6];
    const float* Wout    = (const float*)d_in[7];
    const float* bout    = (const float*)d_in[8];

    float* out  = (float*)d_out;                       // (B,T,D)
    float* attn = out + (size_t)B_ * T_ * D_;          // (B,T,S)

    char* ws = (char*)d_ws;
    float* wqs          = (float*)ws;                             // 2 MB
    float* OB           = (float*)(ws + (2u << 20));              // 2 MB
    unsigned short* uhb = (unsigned short*)(ws + (4u << 20));     // 1 MB
    unsigned short* CWb = (unsigned short*)(ws + (5u << 20));     // 1 MB

    // one dispatch: all four GEMMs, 16 waves/tile, inline fp32->bf16
    G4 gwq = { output,  Wq,     0, bq,      wqs, 1 };
    G4 guh = { context, Wc,     0, nullptr, uhb, 3 };
    G4 gob = { output,  Wout, 512, bout,    OB,  4 };
    G4 gcw = { context, Wout,   0, nullptr, CWb, 5 };
    gemm4<<<dim3(512), dim3(1024), 0, stream>>>(gwq, guh, gob, gcw);

    // fused score + softmax + out-projection
    attn_fused<<<dim3(B_ * T_ / TB), dim3(1024), 0, stream>>>(
        wqs, uhb, CWb, OB, mask, v, attn, out);
}